// Round 12
// baseline (24.447 us; speedup 1.0000x reference)
//
#include <hip/hip_runtime.h>

#define TPB 64          // one wave per block — wave-synchronous, no barriers

struct M3 { float a[9]; };
struct V3 { float x, y, z; };

__device__ __forceinline__ void fence_lgkm() {
    asm volatile("s_waitcnt lgkmcnt(0)" ::: "memory");
    __builtin_amdgcn_wave_barrier();
}

// rotation from 6 floats held in three float2 registers
__device__ __forceinline__ M3 rot6d2(const float2* v) {
    float x0 = v[0].x, x1 = v[0].y, x2 = v[1].x;
    float y0 = v[1].y, y1 = v[2].x, y2 = v[2].y;
    float inx = rsqrtf(fmaxf(x0*x0 + x1*x1 + x2*x2, 1e-16f));
    x0 *= inx; x1 *= inx; x2 *= inx;
    float z0 = x1*y2 - x2*y1;
    float z1 = x2*y0 - x0*y2;
    float z2 = x0*y1 - x1*y0;
    float inz = rsqrtf(fmaxf(z0*z0 + z1*z1 + z2*z2, 1e-16f));
    z0 *= inz; z1 *= inz; z2 *= inz;
    float w0 = z1*x2 - z2*x1;
    float w1 = z2*x0 - z0*x2;
    float w2 = z0*x1 - z1*x0;
    M3 R;
    R.a[0] = x0; R.a[1] = w0; R.a[2] = z0;
    R.a[3] = x1; R.a[4] = w1; R.a[5] = z1;
    R.a[6] = x2; R.a[7] = w2; R.a[8] = z2;
    return R;
}

__device__ __forceinline__ M3 m3mul(const M3& A, const M3& B) {
    M3 C;
#pragma unroll
    for (int r = 0; r < 3; ++r)
#pragma unroll
        for (int c = 0; c < 3; ++c)
            C.a[3*r + c] = A.a[3*r + 0] * B.a[0 + c]
                         + A.a[3*r + 1] * B.a[3 + c]
                         + A.a[3*r + 2] * B.a[6 + c];
    return C;
}

__device__ __forceinline__ V3 step(const M3& P, V3 pp, int axis, float s) {
    V3 q;
    q.x = pp.x + s * P.a[0 + axis];
    q.y = pp.y + s * P.a[3 + axis];
    q.z = pp.z + s * P.a[6 + axis];
    return q;
}

__device__ __forceinline__ void put(float* so, int j, V3 q) {
    so[3*j + 0] = q.x; so[3*j + 1] = q.y; so[3*j + 2] = q.z;
}

// FK from per-joint register float2 triples, results straight to LDS overlay.
// v[u] maps to joints {0,1,2,4,5,7,8,9,11,12,14,15}.
__device__ __forceinline__ void fk_from_regs(const float2 v[12][3], float* so,
                                             const float* len,
                                             float rx, float ry, float rz) {
    V3 q0; q0.x = rx; q0.y = ry; q0.z = rz;
    so[0] = rx; so[1] = ry; so[2] = rz;
    M3 W0 = rot6d2(v[0]);

    // chain 0 -> 1 -> 2 -> 3
    M3 W1 = m3mul(W0, rot6d2(v[1]));  V3 q1 = step(W0, q0, 0, -len[0]);  put(so, 1, q1);
    M3 W2 = m3mul(W1, rot6d2(v[2]));  V3 q2 = step(W1, q1, 1, -len[1]);  put(so, 2, q2);
    /* leaf 3 */                      V3 q3 = step(W2, q2, 1, -len[2]);  put(so, 3, q3);

    // chain 0 -> 4 -> 5 -> 6
    M3 W4 = m3mul(W0, rot6d2(v[3]));  V3 q4 = step(W0, q0, 0,  len[3]);  put(so, 4, q4);
    M3 W5 = m3mul(W4, rot6d2(v[4]));  V3 q5 = step(W4, q4, 1, -len[4]);  put(so, 5, q5);
    /* leaf 6 */                      V3 q6 = step(W5, q5, 1, -len[5]);  put(so, 6, q6);

    // chain 0 -> 7 -> 8
    M3 W7 = m3mul(W0, rot6d2(v[5]));  V3 q7 = step(W0, q0, 1,  len[6]);  put(so, 7, q7);
    M3 W8 = m3mul(W7, rot6d2(v[6]));  V3 q8 = step(W7, q7, 1,  len[7]);  put(so, 8, q8);

    // chain 8 -> 9 -> 10
    M3 W9 = m3mul(W8, rot6d2(v[7]));  V3 q9 = step(W8, q8, 1,  len[8]);  put(so, 9, q9);
    /* leaf 10 */                     V3 q10 = step(W9, q9, 1, len[9]);  put(so, 10, q10);

    // chain 8 -> 11 -> 12 -> 13
    M3 W11 = m3mul(W8,  rot6d2(v[8]));  V3 q11 = step(W8,  q8,  0, len[10]); put(so, 11, q11);
    M3 W12 = m3mul(W11, rot6d2(v[9]));  V3 q12 = step(W11, q11, 0, len[11]); put(so, 12, q12);
    /* leaf 13 */                       V3 q13 = step(W12, q12, 0, len[12]); put(so, 13, q13);

    // chain 8 -> 14 -> 15 -> 16
    M3 W14 = m3mul(W8,  rot6d2(v[10])); V3 q14 = step(W8,  q8,  0, -len[13]); put(so, 14, q14);
    M3 W15 = m3mul(W14, rot6d2(v[11])); V3 q15 = step(W14, q14, 0, -len[14]); put(so, 15, q15);
    /* leaf 16 */                       V3 q16 = step(W15, q15, 0, -len[15]); put(so, 16, q16);
}

__device__ __forceinline__ void load_sample(const float* __restrict__ rot,
                                            long long gs, float2 v[12][3]) {
    constexpr int UJ[12] = {0, 1, 2, 4, 5, 7, 8, 9, 11, 12, 14, 15};
    const float2* g2 = (const float2*)(rot + (size_t)gs * 102);   // 8B-aligned
#pragma unroll
    for (int u = 0; u < 12; ++u)
#pragma unroll
        for (int k = 0; k < 3; ++k)
            v[u][k] = g2[UJ[u] * 3 + k];
}

// coalesced store of one 64-sample overlay (64*51 floats = 816 float4)
__device__ __forceinline__ void store_tile(float* __restrict__ outp,
                                           const float* s_out, int t) {
    float4* o4 = (float4*)outp;
    const float4* l4 = (const float4*)s_out;
#pragma unroll
    for (int r = 0; r < 12; ++r) o4[r * 64 + t] = l4[r * 64 + t];
    if (t < 48) o4[768 + t] = l4[768 + t];
}

__global__ __launch_bounds__(TPB, 1) void PoseDecoder_kernel(
    const float* __restrict__ rot,    // [BL,17,6]
    const float* __restrict__ bones,  // [B,16]
    const float* __restrict__ root,   // [BL,3]
    float* __restrict__ out,          // [BL,17,3]
    int BL, int L)
{
    __shared__ __align__(16) float s_out[TPB * 51];   // 13056 B, reused A then B
    const int t = threadIdx.x;
    const long long base = (long long)blockIdx.x * 128;

    const bool fast = (base + 128 <= BL) &&
                      (base / L == (base + 127) / L);

    if (fast) {
        const long long gsA = base + t, gsB = base + 64 + t;

        // ---- all loads for BOTH tiles issued up front; compiler inserts
        //      counted vmcnt before each first register use ----
        float2 vA[12][3], vB[12][3];
        load_sample(rot, gsA, vA);
        load_sample(rot, gsB, vB);
        float rAx = root[gsA*3+0], rAy = root[gsA*3+1], rAz = root[gsA*3+2];
        float rBx = root[gsB*3+0], rBy = root[gsB*3+1], rBz = root[gsB*3+2];

        // single bone group for the whole 128-sample block (base%256 in {0,128})
        const float* bl = bones + (size_t)(base / L) * 16;
        float len[16];
#pragma unroll
        for (int k = 0; k < 16; ++k) len[k] = bl[k];

        // ---- tile A: FK (B's loads landing underneath) -> overlay -> store ----
        fk_from_regs(vA, s_out + t * 51, len, rAx, rAy, rAz);
        fence_lgkm();                     // overlay writes visible wave-wide
        store_tile(out + (size_t)base * 51, s_out, t);
        fence_lgkm();                     // store's ds_reads retired before reuse

        // ---- tile B: FK (A's global stores draining underneath) ----
        fk_from_regs(vB, s_out + t * 51, len, rBx, rBy, rBz);
        fence_lgkm();
        store_tile(out + (size_t)(base + 64) * 51, s_out, t);
    } else {
        // generic fallback: per-sample scalar path (unused at BL=131072, L=256)
        for (int half = 0; half < 2; ++half) {
            const long long gs = base + half * 64 + t;
            if (gs >= BL) break;
            float2 v[12][3];
            load_sample(rot, gs, v);
            float rx = root[gs*3+0], ry = root[gs*3+1], rz = root[gs*3+2];
            const float* bl = bones + (size_t)(gs / L) * 16;
            float len[16];
#pragma unroll
            for (int k = 0; k < 16; ++k) len[k] = bl[k];
            float so[51];
            fk_from_regs(v, so, len, rx, ry, rz);
            for (int m = 0; m < 51; ++m) out[gs * 51 + m] = so[m];  // slow, correct
        }
    }
}

extern "C" void kernel_launch(void* const* d_in, const int* in_sizes, int n_in,
                              void* d_out, int out_size, void* d_ws, size_t ws_size,
                              hipStream_t stream) {
    const float* rot   = (const float*)d_in[0];
    const float* bones = (const float*)d_in[1];
    const float* root  = (const float*)d_in[2];
    float* out = (float*)d_out;

    int BL = in_sizes[0] / 102;     // 17 joints * 6
    int B  = in_sizes[1] / 16;      // 16 bones
    int L  = BL / B;

    int grid = (BL + 127) / 128;
    PoseDecoder_kernel<<<grid, TPB, 0, stream>>>(rot, bones, root, out, BL, L);
}

// Round 13
// 22.029 us; speedup vs baseline: 1.1098x; 1.1098x over previous
//
#include <hip/hip_runtime.h>

#define TPB 256         // 4 independent waves per block — no barriers anywhere

struct M3 { float a[9]; };
struct V3 { float x, y, z; };

__device__ __forceinline__ void fence_lgkm() {
    asm volatile("s_waitcnt lgkmcnt(0)" ::: "memory");
    __builtin_amdgcn_wave_barrier();
}

// rotation from 6 floats held in three float2 registers
__device__ __forceinline__ M3 rot6d2(const float2* v) {
    float x0 = v[0].x, x1 = v[0].y, x2 = v[1].x;
    float y0 = v[1].y, y1 = v[2].x, y2 = v[2].y;
    float inx = rsqrtf(fmaxf(x0*x0 + x1*x1 + x2*x2, 1e-16f));
    x0 *= inx; x1 *= inx; x2 *= inx;
    float z0 = x1*y2 - x2*y1;
    float z1 = x2*y0 - x0*y2;
    float z2 = x0*y1 - x1*y0;
    float inz = rsqrtf(fmaxf(z0*z0 + z1*z1 + z2*z2, 1e-16f));
    z0 *= inz; z1 *= inz; z2 *= inz;
    float w0 = z1*x2 - z2*x1;
    float w1 = z2*x0 - z0*x2;
    float w2 = z0*x1 - z1*x0;
    M3 R;
    R.a[0] = x0; R.a[1] = w0; R.a[2] = z0;
    R.a[3] = x1; R.a[4] = w1; R.a[5] = z1;
    R.a[6] = x2; R.a[7] = w2; R.a[8] = z2;
    return R;
}

__device__ __forceinline__ M3 m3mul(const M3& A, const M3& B) {
    M3 C;
#pragma unroll
    for (int r = 0; r < 3; ++r)
#pragma unroll
        for (int c = 0; c < 3; ++c)
            C.a[3*r + c] = A.a[3*r + 0] * B.a[0 + c]
                         + A.a[3*r + 1] * B.a[3 + c]
                         + A.a[3*r + 2] * B.a[6 + c];
    return C;
}

__device__ __forceinline__ V3 step(const M3& P, V3 pp, int axis, float s) {
    V3 q;
    q.x = pp.x + s * P.a[0 + axis];
    q.y = pp.y + s * P.a[3 + axis];
    q.z = pp.z + s * P.a[6 + axis];
    return q;
}

__device__ __forceinline__ void put(float* so, int j, V3 q) {
    so[3*j + 0] = q.x; so[3*j + 1] = q.y; so[3*j + 2] = q.z;
}

// FK from per-joint register float2 triples, results straight to LDS overlay.
// v[u] maps to joints {0,1,2,4,5,7,8,9,11,12,14,15}.
__device__ __forceinline__ void fk_from_regs(const float2 v[12][3], float* so,
                                             const float* len,
                                             float rx, float ry, float rz) {
    V3 q0; q0.x = rx; q0.y = ry; q0.z = rz;
    so[0] = rx; so[1] = ry; so[2] = rz;
    M3 W0 = rot6d2(v[0]);

    // chain 0 -> 1 -> 2 -> 3
    M3 W1 = m3mul(W0, rot6d2(v[1]));  V3 q1 = step(W0, q0, 0, -len[0]);  put(so, 1, q1);
    M3 W2 = m3mul(W1, rot6d2(v[2]));  V3 q2 = step(W1, q1, 1, -len[1]);  put(so, 2, q2);
    /* leaf 3 */                      V3 q3 = step(W2, q2, 1, -len[2]);  put(so, 3, q3);

    // chain 0 -> 4 -> 5 -> 6
    M3 W4 = m3mul(W0, rot6d2(v[3]));  V3 q4 = step(W0, q0, 0,  len[3]);  put(so, 4, q4);
    M3 W5 = m3mul(W4, rot6d2(v[4]));  V3 q5 = step(W4, q4, 1, -len[4]);  put(so, 5, q5);
    /* leaf 6 */                      V3 q6 = step(W5, q5, 1, -len[5]);  put(so, 6, q6);

    // chain 0 -> 7 -> 8
    M3 W7 = m3mul(W0, rot6d2(v[5]));  V3 q7 = step(W0, q0, 1,  len[6]);  put(so, 7, q7);
    M3 W8 = m3mul(W7, rot6d2(v[6]));  V3 q8 = step(W7, q7, 1,  len[7]);  put(so, 8, q8);

    // chain 8 -> 9 -> 10
    M3 W9 = m3mul(W8, rot6d2(v[7]));  V3 q9 = step(W8, q8, 1,  len[8]);  put(so, 9, q9);
    /* leaf 10 */                     V3 q10 = step(W9, q9, 1, len[9]);  put(so, 10, q10);

    // chain 8 -> 11 -> 12 -> 13
    M3 W11 = m3mul(W8,  rot6d2(v[8]));  V3 q11 = step(W8,  q8,  0, len[10]); put(so, 11, q11);
    M3 W12 = m3mul(W11, rot6d2(v[9]));  V3 q12 = step(W11, q11, 0, len[11]); put(so, 12, q12);
    /* leaf 13 */                       V3 q13 = step(W12, q12, 0, len[12]); put(so, 13, q13);

    // chain 8 -> 14 -> 15 -> 16
    M3 W14 = m3mul(W8,  rot6d2(v[10])); V3 q14 = step(W8,  q8,  0, -len[13]); put(so, 14, q14);
    M3 W15 = m3mul(W14, rot6d2(v[11])); V3 q15 = step(W14, q14, 0, -len[14]); put(so, 15, q15);
    /* leaf 16 */                       V3 q16 = step(W15, q15, 0, -len[15]); put(so, 16, q16);
}

__device__ __forceinline__ void load_sample(const float* __restrict__ rot,
                                            long long gs, float2 v[12][3]) {
    constexpr int UJ[12] = {0, 1, 2, 4, 5, 7, 8, 9, 11, 12, 14, 15};
    const float2* g2 = (const float2*)(rot + (size_t)gs * 102);   // 8B-aligned
#pragma unroll
    for (int u = 0; u < 12; ++u)
#pragma unroll
        for (int k = 0; k < 3; ++k)
            v[u][k] = g2[UJ[u] * 3 + k];
}

__global__ __launch_bounds__(TPB) void PoseDecoder_kernel(
    const float* __restrict__ rot,    // [BL,17,6]
    const float* __restrict__ bones,  // [B,16]
    const float* __restrict__ root,   // [BL,3]
    float* __restrict__ out,          // [BL,17,3]
    int BL, int L)
{
    __shared__ __align__(16) float s_out[4 * 64 * 51];   // 4 per-wave overlays, 52224 B
    const int wv = threadIdx.x >> 6;          // wave id 0..3
    const int t  = threadIdx.x & 63;          // lane
    const long long blk_base = (long long)blockIdx.x * 256;
    const long long base = blk_base + (long long)wv * 64;   // this wave's tile
    const long long gs = base + t;
    float* so_wave = s_out + wv * (64 * 51);

    const bool fast = (blk_base + 256 <= BL) &&
                      (blk_base / L == (blk_base + 255) / L);

    if (fast) {
        // ---- per-lane scattered loads straight to registers (r9 pattern) ----
        float2 v[12][3];
        load_sample(rot, gs, v);
        float rx = root[gs*3 + 0], ry = root[gs*3 + 1], rz = root[gs*3 + 2];

        // one bone group per 256-sample block (L multiple of 256) -> SGPRs
        const float* bl = bones + (size_t)(blk_base / L) * 16;
        float len[16];
#pragma unroll
        for (int k = 0; k < 16; ++k) len[k] = bl[k];

        // ---- FK from registers, results straight to this wave's overlay ----
        fk_from_regs(v, so_wave + t * 51, len, rx, ry, rz);
        fence_lgkm();                   // wave-local: overlay writes visible

        // ---- coalesced LDS -> global store of this wave's 64 samples ----
        float4* o4 = (float4*)(out + (size_t)base * 51);
        const float4* l4 = (const float4*)so_wave;
#pragma unroll
        for (int r = 0; r < 12; ++r) o4[r * 64 + t] = l4[r * 64 + t];
        if (t < 48) o4[768 + t] = l4[768 + t];
    } else {
        // generic fallback (partial block / bone-boundary crossing)
        if (gs < BL) {
            float2 v[12][3];
            load_sample(rot, gs, v);
            float rx = root[gs*3+0], ry = root[gs*3+1], rz = root[gs*3+2];
            const float* bl = bones + (size_t)(gs / L) * 16;
            float len[16];
#pragma unroll
            for (int k = 0; k < 16; ++k) len[k] = bl[k];
            float so[51];
            fk_from_regs(v, so, len, rx, ry, rz);
            for (int m = 0; m < 51; ++m) out[gs * 51 + m] = so[m];  // slow, correct
        }
    }
}

extern "C" void kernel_launch(void* const* d_in, const int* in_sizes, int n_in,
                              void* d_out, int out_size, void* d_ws, size_t ws_size,
                              hipStream_t stream) {
    const float* rot   = (const float*)d_in[0];
    const float* bones = (const float*)d_in[1];
    const float* root  = (const float*)d_in[2];
    float* out = (float*)d_out;

    int BL = in_sizes[0] / 102;     // 17 joints * 6
    int B  = in_sizes[1] / 16;      // 16 bones
    int L  = BL / B;

    int grid = (BL + 255) / 256;
    PoseDecoder_kernel<<<grid, TPB, 0, stream>>>(rot, bones, root, out, BL, L);
}